// Round 11
// baseline (408.591 us; speedup 1.0000x reference)
//
#include <hip/hip_runtime.h>
#include <hip/hip_bf16.h>
#include <math.h>

#define N_HEAD 16
#define D_HEAD 64
#define T_SEQ 1024
#define BATCH 4
// 1/sqrt(64) * log2(e): Q pre-scaled so scores are in log2 units (exp2 softmax)
#define QSCALE 0.180336879f

typedef float f32x4 __attribute__((ext_vector_type(4)));
typedef short bf16x8 __attribute__((ext_vector_type(8)));
typedef short bf16x4v __attribute__((ext_vector_type(4)));

#define AS1(p) ((const __attribute__((address_space(1))) void*)(p))
#define AS3(p) ((__attribute__((address_space(3))) void*)(p))

// load 8 consecutive bf16 from LDS that are only 8B-aligned (stride 68)
__device__ inline bf16x8 ld8(const __hip_bfloat16* p) {
    bf16x4v lo = *(const bf16x4v*)p;
    bf16x4v hi = *(const bf16x4v*)(p + 4);
    return __builtin_shufflevector(lo, hi, 0, 1, 2, 3, 4, 5, 6, 7);
}

// ---------------------------------------------------------------------------
// Manual grid barrier (replaces hipLaunchCooperativeKernel, which failed to
// launch in r10). Device globals are zero-initialized at module load; count
// self-resets each barrier, generation is monotonic -> reusable across the
// correctness call and all graph replays. Safe because all 512 blocks are
// guaranteed co-resident: launch_bounds(256,2) caps VGPR<=256 (2 waves/SIMD),
// LDS 60KB*2=120<=160KB/CU -> 2 blocks/CU * 256 CUs = 512.
// __threadfence() = agent fence -> buffer_wbl2/buffer_inv on gfx950, giving
// cross-XCD visibility (what grid.sync() does internally).
// ---------------------------------------------------------------------------
__device__ unsigned g_count = 0;
__device__ unsigned g_gen = 0;

__device__ __forceinline__ void grid_barrier() {
    __syncthreads();
    if (threadIdx.x == 0) {
        __threadfence();
        unsigned gen = __hip_atomic_load(&g_gen, __ATOMIC_RELAXED, __HIP_MEMORY_SCOPE_AGENT);
        unsigned t = __hip_atomic_fetch_add(&g_count, 1u, __ATOMIC_ACQ_REL, __HIP_MEMORY_SCOPE_AGENT);
        if (t == 511u) {
            __hip_atomic_store(&g_count, 0u, __ATOMIC_RELAXED, __HIP_MEMORY_SCOPE_AGENT);
            __hip_atomic_fetch_add(&g_gen, 1u, __ATOMIC_RELEASE, __HIP_MEMORY_SCOPE_AGENT);
        } else {
            while (__hip_atomic_load(&g_gen, __ATOMIC_RELAXED, __HIP_MEMORY_SCOPE_AGENT) == gen) {
                __builtin_amdgcn_s_sleep(16);
            }
        }
        __threadfence();
    }
    __syncthreads();
}

// LDS union across phases (max = flash: 60 KB). 2 blocks/CU co-resident.
union SMem {
    struct {
        __hip_bfloat16 As[128 * 32];
        __hip_bfloat16 Bs[192 * 32];
    } g1;                                        // qkv: 20 KB
    struct {
        __hip_bfloat16 Ks[64][72];
        __hip_bfloat16 Vs[64][72];
        __hip_bfloat16 Pl[4][16][68];
        __hip_bfloat16 Pband[4][2][16][68];
        __hip_bfloat16 QPl[4][2][16][66];
    } fl;                                        // flash: 60 KB
    struct {
        __hip_bfloat16 As[128 * 32];
        __hip_bfloat16 Bs[64 * 32];
    } g2;                                        // out: 12 KB
};

// ---------------------------------------------------------------------------
// Persistent mega-kernel: cast -> qkv GEMM -> flash attention -> out GEMM,
// manual grid barriers between phases. 512 blocks x 256 threads, 2 blocks/CU.
// ---------------------------------------------------------------------------
__global__ __launch_bounds__(256, 2) void mega(
    const float* __restrict__ w, const float* __restrict__ Wqkv,
    const float* __restrict__ P, const float* __restrict__ Wo,
    float* __restrict__ out,
    __hip_bfloat16* wb, __hip_bfloat16* Wqkvb, __hip_bfloat16* Wob,
    __hip_bfloat16* Qb, __hip_bfloat16* Kb, __hip_bfloat16* Vtb,
    __hip_bfloat16* AVb) {
    __shared__ SMem sm;

    const int bid = blockIdx.x;       // 0..511
    const int tid = threadIdx.x;
    const int wv = tid >> 6, lane = tid & 63;
    const int lanelo = lane & 15, quad = lane >> 4;

    // ===================== Phase 0: fp32 -> bf16 casts =====================
    {
        const int n0 = 4096 * 1024, n1 = 3072 * 1024, n2 = 1024 * 1024;
        const int ntot = (n0 + n1 + n2) / 8;     // 1,048,576 groups
        for (int g = bid * 256 + tid; g < ntot; g += 512 * 256) {
            int i = g * 8;
            const float* src;
            __hip_bfloat16* dst;
            if (i < n0) { src = w + i; dst = wb + i; }
            else if ((i -= n0) < n1) { src = Wqkv + i; dst = Wqkvb + i; }
            else { i -= n1; src = Wo + i; dst = Wob + i; }
            float4 a = *(const float4*)src;
            float4 b = *(const float4*)(src + 4);
            __hip_bfloat16 t[8];
            t[0] = __float2bfloat16(a.x); t[1] = __float2bfloat16(a.y);
            t[2] = __float2bfloat16(a.z); t[3] = __float2bfloat16(a.w);
            t[4] = __float2bfloat16(b.x); t[5] = __float2bfloat16(b.y);
            t[6] = __float2bfloat16(b.z); t[7] = __float2bfloat16(b.w);
            *(uint4*)dst = *(const uint4*)t;
        }
    }
    grid_barrier();

    // ===================== Phase 1: QKV GEMM (128x192, BK=32) ==============
    {
        constexpr int Kd = 1024;
        const int my = bid >> 4, nx = bid & 15;   // 32 x 16 tiles
        const int m0 = my * 128, n0 = nx * 192;
        const int wm = (wv >> 1) * 64, wn = (wv & 1) * 96;
        __hip_bfloat16* As = sm.g1.As;
        __hip_bfloat16* Bs = sm.g1.Bs;

        const __hip_bfloat16* Ag = wb + (size_t)(m0 + wv * 16 + (lane >> 2)) * Kd + (lane & 3) * 8;
        const __hip_bfloat16* Bg = Wqkvb + (size_t)(n0 + wv * 16 + (lane >> 2)) * Kd + (lane & 3) * 8;
        __hip_bfloat16* AsW0 = As + wv * 16 * 32;
        __hip_bfloat16* AsW1 = As + (64 + wv * 16) * 32;
        __hip_bfloat16* BsW0 = Bs + wv * 16 * 32;
        __hip_bfloat16* BsW1 = Bs + (64 + wv * 16) * 32;
        __hip_bfloat16* BsW2 = Bs + (128 + wv * 16) * 32;

        f32x4 acc[4][6];
#pragma unroll
        for (int i = 0; i < 4; i++)
#pragma unroll
            for (int j = 0; j < 6; j++) acc[i][j] = (f32x4){0.f, 0.f, 0.f, 0.f};

        for (int k0 = 0; k0 < Kd; k0 += 32) {
            __syncthreads();
            __builtin_amdgcn_global_load_lds(AS1(Ag + k0), AS3(AsW0), 16, 0, 0);
            __builtin_amdgcn_global_load_lds(AS1(Ag + 64 * Kd + k0), AS3(AsW1), 16, 0, 0);
            __builtin_amdgcn_global_load_lds(AS1(Bg + k0), AS3(BsW0), 16, 0, 0);
            __builtin_amdgcn_global_load_lds(AS1(Bg + 64 * Kd + k0), AS3(BsW1), 16, 0, 0);
            __builtin_amdgcn_global_load_lds(AS1(Bg + 128 * Kd + k0), AS3(BsW2), 16, 0, 0);
            __syncthreads();
            bf16x8 af[4], bfr[6];
#pragma unroll
            for (int i = 0; i < 4; i++)
                af[i] = *(const bf16x8*)(As + (wm + i * 16 + lanelo) * 32 + quad * 8);
#pragma unroll
            for (int j = 0; j < 6; j++)
                bfr[j] = *(const bf16x8*)(Bs + (wn + j * 16 + lanelo) * 32 + quad * 8);
#pragma unroll
            for (int i = 0; i < 4; i++)
#pragma unroll
                for (int j = 0; j < 6; j++)
                    acc[i][j] = __builtin_amdgcn_mfma_f32_16x16x32_bf16(af[i], bfr[j], acc[i][j], 0, 0, 0);
        }

        const int colbase = n0 + wn;
        float p0v[6];
#pragma unroll
        for (int j = 0; j < 6; j++) p0v[j] = P[(colbase + j * 16 + lanelo) & 63];
#pragma unroll
        for (int i = 0; i < 4; i++)
#pragma unroll
            for (int j = 0; j < 6; j++)
#pragma unroll
                for (int reg = 0; reg < 4; reg++) {
                    const int row = m0 + wm + i * 16 + quad * 4 + reg;  // m = t*4+b
                    const int col = colbase + j * 16 + lanelo;
                    const int part = col >> 10;
                    const int e = col & 1023, h = e >> 6, d = e & 63;
                    const int t = row >> 2, bb = row & 3;
                    const float v = acc[i][j][reg];
                    if (part == 0)
                        Qb[((size_t)(bb * 16 + h) * 1024 + t) * 64 + d] = __float2bfloat16(v * QSCALE);
                    else if (part == 1)
                        Kb[((size_t)(bb * 16 + h) * 1024 + t) * 64 + d] = __float2bfloat16(v);
                    else
                        Vtb[((size_t)(bb * 16 + h) * 64 + d) * 1024 + t] = __float2bfloat16(v + p0v[j]);
                }
    }
    grid_barrier();

    // ===================== Phase 2: flash attention ========================
    {
        const int px = bid & 7;            // 0..7
        const int bh = bid >> 3;           // 0..63
        const int TB = 15 - px, TS = px;
        const int b = bh >> 4, h = bh & 15;
        const size_t qkbase = (size_t)bh * 1024 * 64;
        const size_t vbase  = (size_t)bh * 64 * 1024;
        auto& Ks = sm.fl.Ks;
        auto& Vs = sm.fl.Vs;
        auto& Pl = sm.fl.Pl;
        auto& Pband = sm.fl.Pband;
        auto& QPl = sm.fl.QPl;
        const int w_ = wv;

        const int sr = tid >> 2;
        const int sc = (tid & 3) << 4;
        const __hip_bfloat16* kgb = Kb + qkbase + (size_t)sr * 64 + sc;
        const __hip_bfloat16* vgb = Vtb + vbase + (size_t)sr * 1024 + sc;

        {
            short* pb = (short*)&Pband[w_][0][0][0];
            for (int i = lane; i < 2 * 16 * 68; i += 64) pb[i] = 0;
        }

        bf16x8 aqb0, aqb1, aqs0, aqs1;
        {
            const __hip_bfloat16* qrb = Qb + qkbase + (size_t)(TB * 64 + w_ * 16 + lanelo) * 64;
            aqb0 = *(const bf16x8*)(qrb + quad * 8);
            aqb1 = *(const bf16x8*)(qrb + 32 + quad * 8);
            const __hip_bfloat16* qrs = Qb + qkbase + (size_t)(TS * 64 + w_ * 16 + lanelo) * 64;
            aqs0 = *(const bf16x8*)(qrs + quad * 8);
            aqs1 = *(const bf16x8*)(qrs + 32 + quad * 8);
        }

#pragma unroll
        for (int jj = 0; jj < 5; jj++) {
            const float* prow = P + (size_t)(jj * 16 + lanelo) * 64 + quad * 8;
            float4 pa = *(const float4*)prow;
            float4 pb = *(const float4*)(prow + 4);
            float4 pc = *(const float4*)(prow + 32);
            float4 pd = *(const float4*)(prow + 36);
            __hip_bfloat16 t0[8], t1[8];
            t0[0] = __float2bfloat16(pa.x); t0[1] = __float2bfloat16(pa.y);
            t0[2] = __float2bfloat16(pa.z); t0[3] = __float2bfloat16(pa.w);
            t0[4] = __float2bfloat16(pb.x); t0[5] = __float2bfloat16(pb.y);
            t0[6] = __float2bfloat16(pb.z); t0[7] = __float2bfloat16(pb.w);
            t1[0] = __float2bfloat16(pc.x); t1[1] = __float2bfloat16(pc.y);
            t1[2] = __float2bfloat16(pc.z); t1[3] = __float2bfloat16(pc.w);
            t1[4] = __float2bfloat16(pd.x); t1[5] = __float2bfloat16(pd.y);
            t1[6] = __float2bfloat16(pd.z); t1[7] = __float2bfloat16(pd.w);
            f32x4 accB = (f32x4){0.f, 0.f, 0.f, 0.f};
            accB = __builtin_amdgcn_mfma_f32_16x16x32_bf16(aqb0, *(const bf16x8*)t0, accB, 0, 0, 0);
            accB = __builtin_amdgcn_mfma_f32_16x16x32_bf16(aqb1, *(const bf16x8*)t1, accB, 0, 0, 0);
            f32x4 accS = (f32x4){0.f, 0.f, 0.f, 0.f};
            accS = __builtin_amdgcn_mfma_f32_16x16x32_bf16(aqs0, *(const bf16x8*)t0, accS, 0, 0, 0);
            accS = __builtin_amdgcn_mfma_f32_16x16x32_bf16(aqs1, *(const bf16x8*)t1, accS, 0, 0, 0);
#pragma unroll
            for (int reg = 0; reg < 4; reg++) {
                QPl[w_][0][quad * 4 + reg][jj * 16 + lanelo] = __float2bfloat16(accB[reg]);
                QPl[w_][1][quad * 4 + reg][jj * 16 + lanelo] = __float2bfloat16(accS[reg]);
            }
        }
        float qp0b[4], qp0s[4];
#pragma unroll
        for (int reg = 0; reg < 4; reg++) {
            qp0b[reg] = (float)QPl[w_][0][quad * 4 + reg][0];
            qp0s[reg] = (float)QPl[w_][1][quad * 4 + reg][0];
        }

        f32x4 o_accB[4], o_lB, o_accS[4], o_lS;
#pragma unroll
        for (int dt = 0; dt < 4; dt++) {
            o_accB[dt] = (f32x4){0.f, 0.f, 0.f, 0.f};
            o_accS[dt] = (f32x4){0.f, 0.f, 0.f, 0.f};
        }
        o_lB = (f32x4){0.f, 0.f, 0.f, 0.f};
        o_lS = (f32x4){0.f, 0.f, 0.f, 0.f};
        const short one_bf = 0x3F80;
        const bf16x8 vones = {one_bf, one_bf, one_bf, one_bf, one_bf, one_bf, one_bf, one_bf};

        auto do_qtile = [&](int tq, int Tq, const bf16x8& a0, const bf16x8& a1,
                            const float* qp0, f32x4* o_acc, f32x4& o_l, int kt) {
            f32x4 s_acc[4];
#pragma unroll
            for (int ct = 0; ct < 4; ct++) {
                bf16x8 b0 = *(const bf16x8*)&Ks[ct * 16 + lanelo][quad * 8];
                bf16x8 b1 = *(const bf16x8*)&Ks[ct * 16 + lanelo][32 + quad * 8];
                f32x4 acc = (f32x4){0.f, 0.f, 0.f, 0.f};
                acc = __builtin_amdgcn_mfma_f32_16x16x32_bf16(a0, b0, acc, 0, 0, 0);
                acc = __builtin_amdgcn_mfma_f32_16x16x32_bf16(a1, b1, acc, 0, 0, 0);
                s_acc[ct] = acc;
            }
            const int q0 = Tq * 64 + w_ * 16;
            const int obase = q0 - kt * 64;
            if (kt < Tq - 1) {
#pragma unroll
                for (int ct = 0; ct < 4; ct++)
#pragma unroll
                    for (int reg = 0; reg < 4; reg++) {
                        const float p = __builtin_exp2f(s_acc[ct][reg] + qp0[reg]);
                        Pl[w_][quad * 4 + reg][ct * 16 + lanelo] = __float2bfloat16(p);
                    }
            } else {
#pragma unroll
                for (int ct = 0; ct < 4; ct++)
#pragma unroll
                    for (int reg = 0; reg < 4; reg++) {
                        const int rloc = quad * 4 + reg;
                        const int kl = ct * 16 + lanelo;
                        const int o = obase + rloc - kl;
                        const int idx = (o >= 64 || o < 0) ? 0 : (64 - o);
                        const float add = (float)QPl[w_][tq][rloc][idx];
                        const float p = (o < 0) ? 0.f : __builtin_exp2f(s_acc[ct][reg] + add);
                        const __hip_bfloat16 pbv = __float2bfloat16(p);
                        Pl[w_][rloc][kl] = pbv;
                        if (o >= 0 && o <= 63) Pband[w_][tq][rloc][63 - o] = pbv;
                    }
            }
#pragma unroll
            for (int c = 0; c < 2; c++) {
                bf16x8 ap = ld8(&Pl[w_][lanelo][c * 32 + quad * 8]);
#pragma unroll
                for (int dt = 0; dt < 4; dt++) {
                    bf16x8 bv = *(const bf16x8*)&Vs[dt * 16 + lanelo][c * 32 + quad * 8];
                    o_acc[dt] = __builtin_amdgcn_mfma_f32_16x16x32_bf16(ap, bv, o_acc[dt], 0, 0, 0);
                }
                o_l = __builtin_amdgcn_mfma_f32_16x16x32_bf16(ap, vones, o_l, 0, 0, 0);
            }
        };

        uint4 rk0, rk1, rv0, rv1;
        rk0 = *(const uint4*)(kgb);
        rk1 = *(const uint4*)(kgb + 8);
        rv0 = *(const uint4*)(vgb);
        rv1 = *(const uint4*)(vgb + 8);

        for (int kt = 0; kt <= TB; kt++) {
            __syncthreads();
            *(uint4*)&Ks[sr][sc]     = rk0;
            *(uint4*)&Ks[sr][sc + 8] = rk1;
            *(uint4*)&Vs[sr][sc]     = rv0;
            *(uint4*)&Vs[sr][sc + 8] = rv1;
            if (kt < TB) {
                const __hip_bfloat16* kg = kgb + (size_t)(kt + 1) * 4096;
                const __hip_bfloat16* vg = vgb + (size_t)(kt + 1) * 64;
                rk0 = *(const uint4*)(kg);
                rk1 = *(const uint4*)(kg + 8);
                rv0 = *(const uint4*)(vg);
                rv1 = *(const uint4*)(vg + 8);
            }
            __syncthreads();

            do_qtile(0, TB, aqb0, aqb1, qp0b, o_accB, o_lB, kt);
            if (kt <= TS) do_qtile(1, TS, aqs0, aqs1, qp0s, o_accS, o_lS, kt);
        }

#pragma unroll
        for (int tq = 0; tq < 2; tq++) {
            f32x4* o_acc = tq == 0 ? o_accB : o_accS;
            f32x4& o_l   = tq == 0 ? o_lB : o_lS;
            const int q0 = (tq == 0 ? TB : TS) * 64 + w_ * 16;
#pragma unroll
            for (int c = 0; c < 2; c++) {
                bf16x8 ab = ld8(&Pband[w_][tq][lanelo][c * 32 + quad * 8]);
#pragma unroll
                for (int dt = 0; dt < 4; dt++) {
                    const int d = dt * 16 + lanelo;
                    const float p0 = P[d];
                    __hip_bfloat16 tb[8];
#pragma unroll
                    for (int jj = 0; jj < 8; jj++) {
                        const int kk = c * 32 + quad * 8 + jj;
                        tb[jj] = __float2bfloat16(P[(kk + 1) * 64 + d] - p0);
                    }
                    o_acc[dt] = __builtin_amdgcn_mfma_f32_16x16x32_bf16(ab, *(const bf16x8*)tb, o_acc[dt], 0, 0, 0);
                }
            }
            float rinv[4];
#pragma unroll
            for (int reg = 0; reg < 4; reg++) rinv[reg] = 1.0f / o_l[reg];
#pragma unroll
            for (int dt = 0; dt < 4; dt++) {
                const int cdim = dt * 16 + lanelo;
#pragma unroll
                for (int reg = 0; reg < 4; reg++) {
                    const int q = q0 + quad * 4 + reg;
                    AVb[((size_t)(b * 1024 + q)) * 1024 + h * 64 + cdim] =
                        __float2bfloat16(o_acc[dt][reg] * rinv[reg]);
                }
            }
        }
    }
    grid_barrier();

    // ===================== Phase 3: out GEMM (128x64, BK=32) ===============
    {
        constexpr int Kd = 1024;
        const int by = bid >> 4, bx = bid & 15;   // 32 x 16 tiles
        const int m0 = by * 128, n0 = bx * 64;
        const int wm = (wv >> 1) * 64, wn = (wv & 1) * 32;
        __hip_bfloat16* As = sm.g2.As;
        __hip_bfloat16* Bs = sm.g2.Bs;

        const __hip_bfloat16* Ag = AVb + (size_t)(m0 + wv * 16 + (lane >> 2)) * Kd + (lane & 3) * 8;
        const __hip_bfloat16* Bg = Wob + (size_t)(n0 + wv * 16 + (lane >> 2)) * Kd + (lane & 3) * 8;
        __hip_bfloat16* AsW0 = As + wv * 16 * 32;
        __hip_bfloat16* AsW1 = As + (64 + wv * 16) * 32;
        __hip_bfloat16* BsW0 = Bs + wv * 16 * 32;

        f32x4 acc[4][2];
#pragma unroll
        for (int i = 0; i < 4; i++)
#pragma unroll
            for (int j = 0; j < 2; j++) acc[i][j] = (f32x4){0.f, 0.f, 0.f, 0.f};

        for (int k0 = 0; k0 < Kd; k0 += 32) {
            __syncthreads();
            __builtin_amdgcn_global_load_lds(AS1(Ag + k0), AS3(AsW0), 16, 0, 0);
            __builtin_amdgcn_global_load_lds(AS1(Ag + 64 * Kd + k0), AS3(AsW1), 16, 0, 0);
            __builtin_amdgcn_global_load_lds(AS1(Bg + k0), AS3(BsW0), 16, 0, 0);
            __syncthreads();
            bf16x8 af[4], bfr[2];
#pragma unroll
            for (int i = 0; i < 4; i++)
                af[i] = *(const bf16x8*)(As + (wm + i * 16 + lanelo) * 32 + quad * 8);
#pragma unroll
            for (int j = 0; j < 2; j++)
                bfr[j] = *(const bf16x8*)(Bs + (wn + j * 16 + lanelo) * 32 + quad * 8);
#pragma unroll
            for (int i = 0; i < 4; i++)
#pragma unroll
                for (int j = 0; j < 2; j++)
                    acc[i][j] = __builtin_amdgcn_mfma_f32_16x16x32_bf16(af[i], bfr[j], acc[i][j], 0, 0, 0);
        }

#pragma unroll
        for (int i = 0; i < 4; i++)
#pragma unroll
            for (int j = 0; j < 2; j++)
#pragma unroll
                for (int reg = 0; reg < 4; reg++) {
                    const int row = m0 + wm + i * 16 + quad * 4 + reg;  // m = b*1024+t
                    const int col = n0 + wn + j * 16 + lanelo;
                    const int bb = row >> 10, t = row & 1023;
                    out[(size_t)(t * 4 + bb) * 1024 + col] = acc[i][j][reg];
                }
    }
}

extern "C" void kernel_launch(void* const* d_in, const int* in_sizes, int n_in,
                              void* d_out, int out_size, void* d_ws, size_t ws_size,
                              hipStream_t stream) {
    const float* w       = (const float*)d_in[0];
    // d_in[1] = attn_mask (deterministic causal; recomputed from indices)
    const float* Wqkv    = (const float*)d_in[2];
    const float* pos_emb = (const float*)d_in[3];
    const float* Wo      = (const float*)d_in[4];
    float* out = (float*)d_out;

    const size_t SZ = (size_t)BATCH * N_HEAD * T_SEQ * D_HEAD;  // 4,194,304
    __hip_bfloat16* wb     = (__hip_bfloat16*)d_ws;
    __hip_bfloat16* Wqkvb  = wb + SZ;
    __hip_bfloat16* Wob    = Wqkvb + 3 * 1024 * 1024;
    __hip_bfloat16* Qb     = Wob + 1024 * 1024;
    __hip_bfloat16* Kb     = Qb + SZ;
    __hip_bfloat16* Vtb    = Kb + SZ;
    __hip_bfloat16* AVb    = Vtb + SZ;

    mega<<<dim3(512), dim3(256), 0, stream>>>(
        w, Wqkv, pos_emb, Wo, out, wb, Wqkvb, Wob, Qb, Kb, Vtb, AVb);
}